// Round 12
// baseline (3695.598 us; speedup 1.0000x reference)
//
#include <hip/hip_runtime.h>
#include <math.h>

typedef _Float16 f16;
typedef f16  f16x8 __attribute__((ext_vector_type(8)));
typedef f16  f16x4 __attribute__((ext_vector_type(4)));
typedef float f32x4 __attribute__((ext_vector_type(4)));

#define NB 64
#define NC 16
#define NF 128
#define ND 256
#define NSTEP 60
#define GRID_ELEMS (NB*64*64*NC)   // 16 MB fp32
#define NPIX (NB*64*64)

#define KCONV 160                  // 9 taps * 16ch padded to 10 taps
#define HSS   136                  // hs row stride (f16): 2-way on b128 (free)
#define HCS   24                   // halo cell stride (f16): 12 banks -> 2-way (free); 16 was 4-way
#define RPS   17                   // redF row stride (fp32): lane*17 mod 32 is a permutation -> conflict-free

// weight buffer layout (f16 elements) inside d_out scratch region
#define OFF_CW 0             // [128][160]
#define OFF_W1 20480         // [256][128]
#define OFF_W2 53248         // [16][256]

// ---------------- init: grid ch0 = input, others 0 ----------------
__global__ void init_grid(const float* __restrict__ inp, float* __restrict__ g) {
    int i = blockIdx.x * 256 + threadIdx.x;
    if (i >= GRID_ELEMS) return;
    int c = i & 15;
    g[i] = (c == 0) ? inp[i >> 4] : 0.0f;
}

// ---------------- prep: f16 transposed weights ----------------
__global__ void prep_weights(const float* __restrict__ cw, const float* __restrict__ w1,
                             const float* __restrict__ w2, f16* __restrict__ wb) {
    int i = blockIdx.x * 256 + threadIdx.x;   // 57344 threads exactly
    float v; int off, idx;
    if (i < 20480) {                          // cwT[f][k], k = tap*16+c (tap9 zero)
        int f = i / 160, k = i - f * 160;
        v = (k < 144) ? cw[k * 128 + f] : 0.0f;
        off = OFF_CW; idx = i;
    } else if (i < 20480 + 32768) {           // w1T[j][f]
        int r = i - 20480;
        int j = r >> 7, f = r & 127;
        v = w1[f * 256 + j];
        off = OFF_W1; idx = r;
    } else {                                  // w2T[c][j]
        int r = i - 20480 - 32768;
        int c = r >> 8, j = r & 255;
        v = w2[j * 16 + c];
        off = OFF_W2; idx = r;
    }
    wb[off + idx] = (f16)v;
}

// ---------------- fused NCA step (pure-f16 MFMA, fp32 accumulate/state) ----------------
// Block = 8x8 px tile (64 px), 256 threads = 4 waves, 22528 B LDS -> up to 7
// blocks/CU by LDS; VGPR 84 allows 6 waves/SIMD. Attacks the latency bound
// (R11: all pipes <26%, occupancy 25%). Same math/order as R11 -> bit-identical.
__global__ __launch_bounds__(256, 3) void nca_step(
    const float* __restrict__ gin, float* __restrict__ gout,
    const f16* __restrict__ wb,
    const float* __restrict__ cb, const float* __restrict__ b1, const float* __restrict__ b2)
{
    // hs[64*136] (17408 B) + union{ halo [100][24] (4800 B) | aScr [64][40] (5120 B) }
    // redF (4*64*17 fp32 = 17408 B) overlays hs after dense phase.
    __shared__ f16 smem[11264];              // 22528 B
    f16* const hs   = smem;                  // 8704 elems
    f16* const un   = smem + 8704;           // 2560 elems
    f16* const halo = un;                    // [yy*10+xx]*24 + c
    f16* const aScr = un;                    // [4w*16px][40]
    float* const redF = (float*)smem;        // [4][64][RPS] fp32

    const int t    = threadIdx.x;
    const int w    = t >> 6;
    const int lane = t & 63;
    const int q    = lane >> 4;
    const int l16  = lane & 15;

    const int bi = blockIdx.x;
    const int b  = bi >> 6;
    const int y0 = ((bi >> 3) & 7) << 3;
    const int x0 = (bi & 7) << 3;

    const float* gb  = gin  + (size_t)b * 64 * 64 * 16;
    float*       gob = gout + (size_t)b * 64 * 64 * 16;

    // ---- conv A-fragments + w2 fragments: issue global loads first ----
    const int fbase = w << 5;                // wave owns 32 filters
    f16x8 cA[2][5];
    #pragma unroll
    for (int ft = 0; ft < 2; ++ft)
        #pragma unroll
        for (int kc = 0; kc < 5; ++kc)
            cA[ft][kc] = *(const f16x8*)(wb + OFF_CW +
                (size_t)(fbase + ft * 16 + l16) * KCONV + kc * 32 + q * 8);
    const int jbase = w << 6;                // wave owns 64 j-columns
    f16x8 w2f[2];
    #pragma unroll
    for (int jp = 0; jp < 2; ++jp)
        w2f[jp] = *(const f16x8*)(wb + OFF_W2 + (size_t)l16 * 256 + jbase + jp * 32 + q * 8);

    // ---- stage halo (f16), zero-pad SAME; f32x4 global reads ----
    for (int i = t; i < 400; i += 256) {     // 100 cells x 4 c-quads
        int c4 = (i & 3) << 2;
        int xy = i >> 2;
        int xx = xy % 10;
        int yy = xy / 10;
        int gy = y0 + yy - 1, gx = x0 + xx - 1;
        f32x4 v = {0.f, 0.f, 0.f, 0.f};
        if ((unsigned)gy < 64u && (unsigned)gx < 64u)
            v = *(const f32x4*)(gb + (gy * 64 + gx) * 16 + c4);
        f16x4 hv;
        hv.x = (f16)v.x; hv.y = (f16)v.y; hv.z = (f16)v.z; hv.w = (f16)v.w;
        *(f16x4*)(halo + xy * HCS + c4) = hv;
    }
    __syncthreads();

    // ================= conv 3x3x16 -> 128, bias, relu =================
    f32x4 acc[2][4];
    #pragma unroll
    for (int ft = 0; ft < 2; ++ft) {
        f32x4 bias;
        bias.x = cb[fbase + ft * 16 + q * 4 + 0];
        bias.y = cb[fbase + ft * 16 + q * 4 + 1];
        bias.z = cb[fbase + ft * 16 + q * 4 + 2];
        bias.w = cb[fbase + ft * 16 + q * 4 + 3];
        #pragma unroll
        for (int p = 0; p < 4; ++p) acc[ft][p] = bias;
    }

    #pragma unroll
    for (int kc = 0; kc < 5; ++kc) {
        int tap = kc * 2 + (q >> 1);
        if (tap > 8) tap = 8;                // k>=144: weights are zero
        int dy = tap / 3, dx = tap - dy * 3;
        #pragma unroll
        for (int p = 0; p < 4; ++p) {
            int yy = p * 2 + (l16 >> 3) + dy;     // px = p*16+l16 -> (px>>3, px&7)
            int xx = (l16 & 7) + dx;
            f16x8 bf = *(const f16x8*)(halo + (yy * 10 + xx) * HCS + (q & 1) * 8);
            #pragma unroll
            for (int ft = 0; ft < 2; ++ft)
                acc[ft][p] = __builtin_amdgcn_mfma_f32_16x16x32_f16(cA[ft][kc], bf, acc[ft][p], 0, 0, 0);
        }
    }

    // relu in fp32, pack f16, write hs[px][f] (b64)
    #pragma unroll
    for (int ft = 0; ft < 2; ++ft)
        #pragma unroll
        for (int p = 0; p < 4; ++p) {
            f32x4 a = acc[ft][p];
            f16x4 pk;
            pk.x = (f16)fmaxf(a.x, 0.0f);
            pk.y = (f16)fmaxf(a.y, 0.0f);
            pk.z = (f16)fmaxf(a.z, 0.0f);
            pk.w = (f16)fmaxf(a.w, 0.0f);
            *(f16x4*)(hs + (p * 16 + l16) * HSS + fbase + ft * 16 + q * 4) = pk;
        }
    __syncthreads();   // hs published; halo region dead -> aScr

    // ============ dense1 (128->256, relu) fused w/ dense2 (256->16) ============
    // All w1 fragments held in registers; p-outer reads each hB once.
    f16x8 dA[2][2][4];
    float b1v[2][2][4];
    #pragma unroll
    for (int jp = 0; jp < 2; ++jp)
        #pragma unroll
        for (int jt2 = 0; jt2 < 2; ++jt2) {
            #pragma unroll
            for (int kc = 0; kc < 4; ++kc)
                dA[jp][jt2][kc] = *(const f16x8*)(wb + OFF_W1 +
                    (size_t)(jbase + jp * 32 + jt2 * 16 + l16) * 128 + kc * 32 + q * 8);
            #pragma unroll
            for (int r = 0; r < 4; ++r)
                b1v[jp][jt2][r] = b1[jbase + jp * 32 + jt2 * 16 + q * 4 + r];
        }

    f32x4 dacc[4];   // PARTIAL over this wave's 64 j
    #pragma unroll
    for (int p = 0; p < 4; ++p) { dacc[p].x = 0.f; dacc[p].y = 0.f; dacc[p].z = 0.f; dacc[p].w = 0.f; }

    f16* const myScr = aScr + (w * 16 + l16) * 40;

    for (int p = 0; p < 4; ++p) {
        f16x8 hB[4];
        #pragma unroll
        for (int kc = 0; kc < 4; ++kc)
            hB[kc] = *(const f16x8*)(hs + (p * 16 + l16) * HSS + kc * 32 + q * 8);

        #pragma unroll
        for (int jp = 0; jp < 2; ++jp) {
            #pragma unroll
            for (int jt2 = 0; jt2 < 2; ++jt2) {
                f32x4 a1;
                a1.x = b1v[jp][jt2][0]; a1.y = b1v[jp][jt2][1];
                a1.z = b1v[jp][jt2][2]; a1.w = b1v[jp][jt2][3];
                #pragma unroll
                for (int kc = 0; kc < 4; ++kc)
                    a1 = __builtin_amdgcn_mfma_f32_16x16x32_f16(dA[jp][jt2][kc], hB[kc], a1, 0, 0, 0);
                f16x4 pk;
                pk.x = (f16)fmaxf(a1.x, 0.0f);
                pk.y = (f16)fmaxf(a1.y, 0.0f);
                pk.z = (f16)fmaxf(a1.z, 0.0f);
                pk.w = (f16)fmaxf(a1.w, 0.0f);
                // D rows j32 = jt2*16+q*4+r, col px=l16 -> scratch[px][j32]
                *(f16x4*)(myScr + jt2 * 16 + q * 4) = pk;
            }
            // in-wave transpose readback: A-op [m=px=l16][k=q*8..]
            f16x8 af = *(const f16x8*)(myScr + q * 8);
            dacc[p] = __builtin_amdgcn_mfma_f32_16x16x32_f16(af, w2f[jp], dacc[p], 0, 0, 0);
        }
    }

    // ---- cross-wave reduction of dense2 partials ----
    __syncthreads();                         // all hs reads done -> redF may overwrite
    #pragma unroll
    for (int p = 0; p < 4; ++p)
        #pragma unroll
        for (int r = 0; r < 4; ++r) {
            int px = p * 16 + q * 4 + r;     // D row -> pixel, col l16 -> channel
            redF[(w * 64 + px) * RPS + l16] = dacc[p][r];
        }
    __syncthreads();

    // thread t: px = t>>2, channels c = (t&3)*4..+3 ; masked residual update
    {
        const int px = t >> 2;
        const int cq = (t & 3) << 2;
        const int yy = px >> 3, xx = px & 7;
        const size_t pixb = ((size_t)(y0 + yy) * 64 + (x0 + xx)) * 16;
        const float a0 = gb[pixb];           // exact fp32 ch0
        const bool alive = (a0 > 0.1f);
        f32x4 s0 = *(const f32x4*)(redF + (0 * 64 + px) * RPS + cq);
        f32x4 s1 = *(const f32x4*)(redF + (1 * 64 + px) * RPS + cq);
        f32x4 s2 = *(const f32x4*)(redF + (2 * 64 + px) * RPS + cq);
        f32x4 s3 = *(const f32x4*)(redF + (3 * 64 + px) * RPS + cq);
        f32x4 sv = s0 + s1 + s2 + s3;
        f32x4 gv = *(const f32x4*)(gb + pixb + cq);
        f32x4 ov;
        #pragma unroll
        for (int i = 0; i < 4; ++i) {
            int c = cq + i;
            float nv = gv[i];
            if (alive && c != 0) nv += sv[i] + b2[c];
            ov[i] = nv;
        }
        *(f32x4*)(gob + pixb + cq) = ov;
    }
}

// ---------------- final softmax over channels 1..10 ----------------
__global__ void softmax_out(const float* __restrict__ g, float* __restrict__ out) {
    int pix = blockIdx.x * 256 + threadIdx.x;
    if (pix >= NPIX) return;
    const float* gp = g + (size_t)pix * 16;
    float v[10];
    float m = -1e30f;
    #pragma unroll
    for (int i = 0; i < 10; ++i) { v[i] = gp[1 + i]; m = fmaxf(m, v[i]); }
    float s = 0.f;
    #pragma unroll
    for (int i = 0; i < 10; ++i) { v[i] = __expf(v[i] - m); s += v[i]; }
    float inv = 1.0f / s;
    float* op = out + (size_t)pix * 10;
    #pragma unroll
    for (int i = 0; i < 10; ++i) op[i] = v[i] * inv;
}

extern "C" void kernel_launch(void* const* d_in, const int* in_sizes, int n_in,
                              void* d_out, int out_size, void* d_ws, size_t ws_size,
                              hipStream_t stream) {
    const float* inp = (const float*)d_in[0];
    const float* cw  = (const float*)d_in[1];
    const float* cb  = (const float*)d_in[2];
    const float* w1  = (const float*)d_in[3];
    const float* b1  = (const float*)d_in[4];
    const float* w2  = (const float*)d_in[5];
    const float* b2  = (const float*)d_in[6];
    float* out = (float*)d_out;

    // grid double-buffer in d_ws (32 MB, proven)
    float* g0 = (float*)d_ws;
    float* g1 = g0 + GRID_ELEMS;
    // f16 weights in d_out scratch (115 KB of 10.48 MB; softmax overwrites at end)
    f16* wb = (f16*)d_out;

    prep_weights<<<224, 256, 0, stream>>>(cw, w1, w2, wb);
    init_grid<<<(GRID_ELEMS + 255) / 256, 256, 0, stream>>>(inp, g0);

    float* bufs[2] = { g0, g1 };
    for (int s = 0; s < NSTEP; ++s) {
        nca_step<<<4096, 256, 0, stream>>>(bufs[s & 1], bufs[(s + 1) & 1],
                                           wb, cb, b1, b2);
    }
    // NSTEP=60 even -> final state in g0
    softmax_out<<<(NPIX + 255) / 256, 256, 0, stream>>>(g0, out);
}

// Round 13
// 2610.976 us; speedup vs baseline: 1.4154x; 1.4154x over previous
//
#include <hip/hip_runtime.h>
#include <math.h>

typedef _Float16 f16;
typedef f16  f16x8 __attribute__((ext_vector_type(8)));
typedef f16  f16x4 __attribute__((ext_vector_type(4)));
typedef float f32x4 __attribute__((ext_vector_type(4)));

#define NB 64
#define NC 16
#define NF 128
#define ND 256
#define NSTEP 60
#define GRID_ELEMS (NB*64*64*NC)   // 16 MB fp32
#define NPIX (NB*64*64)

#define KCONV 160                  // 9 taps * 16ch padded to 10 taps
#define HSS   136                  // hs row stride (f16) — R11-proven
#define RPS   18                   // redF row stride (fp32): quad stride 72≡8 mod 32 -> 2-way (free)

// weight buffer layout (f16 elements) inside d_out scratch region
#define OFF_CW 0             // [128][160]
#define OFF_W1 20480         // [256][128]
#define OFF_W2 53248         // [16][256]

// ---------------- init: grid ch0 = input, others 0 ----------------
__global__ void init_grid(const float* __restrict__ inp, float* __restrict__ g) {
    int i = blockIdx.x * 256 + threadIdx.x;
    if (i >= GRID_ELEMS) return;
    int c = i & 15;
    g[i] = (c == 0) ? inp[i >> 4] : 0.0f;
}

// ---------------- prep: f16 transposed weights ----------------
__global__ void prep_weights(const float* __restrict__ cw, const float* __restrict__ w1,
                             const float* __restrict__ w2, f16* __restrict__ wb) {
    int i = blockIdx.x * 256 + threadIdx.x;   // 57344 threads exactly
    float v; int off, idx;
    if (i < 20480) {                          // cwT[f][k], k = tap*16+c (tap9 zero)
        int f = i / 160, k = i - f * 160;
        v = (k < 144) ? cw[k * 128 + f] : 0.0f;
        off = OFF_CW; idx = i;
    } else if (i < 20480 + 32768) {           // w1T[j][f]
        int r = i - 20480;
        int j = r >> 7, f = r & 127;
        v = w1[f * 256 + j];
        off = OFF_W1; idx = r;
    } else {                                  // w2T[c][j]
        int r = i - 20480 - 32768;
        int c = r >> 8, j = r & 255;
        v = w2[j * 16 + c];
        off = OFF_W2; idx = r;
    }
    wb[off + idx] = (f16)v;
}

// ---------------- fused NCA step (pure-f16 MFMA, fp32 accumulate/state) ----------------
// Block = 16x16 px tile (256 px), 256 threads = 4 waves, 1024 blocks/step.
// Amortizes the measured ~17 us/step per-block fixed overhead (R11 vs R12 fit)
// over 2x the pixels. Per-pixel math/order identical to R11 -> bit-identical absmax.
// 80000 B LDS -> 2 blocks/CU; dense dacc[16] accumulators live in AGPRs.
__global__ __launch_bounds__(256, 2) void nca_step(
    const float* __restrict__ gin, float* __restrict__ gout,
    const f16* __restrict__ wb,
    const float* __restrict__ cb, const float* __restrict__ b1, const float* __restrict__ b2)
{
    // hs[256*136] (69632 B) + union{ halo [18*18][16] (10368 B) | aScr [64][40] (5120 B) }
    // redF (4*256*18 fp32 = 73728 B) overlays everything after dense phase.
    __shared__ f16 smem[40000];              // 80000 B
    f16* const hs   = smem;                  // 34816 elems
    f16* const un   = smem + 34816;          // 5184 elems
    f16* const halo = un;                    // [(hy*18+hx)]*16 + c ; cell(hy,hx) = image(y0+hy-1, x0+hx-1)
    f16* const aScr = un;                    // [4w*16px][40]
    float* const redF = (float*)smem;        // [4][256][RPS] fp32

    const int t    = threadIdx.x;
    const int w    = t >> 6;
    const int lane = t & 63;
    const int q    = lane >> 4;
    const int l16  = lane & 15;

    const int bi = blockIdx.x;
    const int b  = bi >> 4;
    const int tl = bi & 15;
    const int y0 = (tl >> 2) << 4;
    const int x0 = (tl & 3) << 4;

    const float* gb  = gin  + (size_t)b * 64 * 64 * 16;
    float*       gob = gout + (size_t)b * 64 * 64 * 16;

    // ---- conv A-fragments + w2 fragments: issue global loads first ----
    const int fbase = w << 5;                // wave owns 32 filters
    f16x8 cA[2][5];
    #pragma unroll
    for (int ft = 0; ft < 2; ++ft)
        #pragma unroll
        for (int kc = 0; kc < 5; ++kc)
            cA[ft][kc] = *(const f16x8*)(wb + OFF_CW +
                (size_t)(fbase + ft * 16 + l16) * KCONV + kc * 32 + q * 8);
    const int jbase = w << 6;                // wave owns 64 j-columns
    f16x8 w2f[2];
    #pragma unroll
    for (int jp = 0; jp < 2; ++jp)
        w2f[jp] = *(const f16x8*)(wb + OFF_W2 + (size_t)l16 * 256 + jbase + jp * 32 + q * 8);

    // ---- stage halo (f16), zero-pad SAME; f32x4 global reads ----
    for (int i = t; i < 1296; i += 256) {    // 324 cells x 4 c-quads
        int c4 = (i & 3) << 2;
        int xy = i >> 2;
        int xx = xy % 18;
        int yy = xy / 18;
        int gy = y0 + yy - 1, gx = x0 + xx - 1;
        f32x4 v = {0.f, 0.f, 0.f, 0.f};
        if ((unsigned)gy < 64u && (unsigned)gx < 64u)
            v = *(const f32x4*)(gb + (gy * 64 + gx) * 16 + c4);
        f16x4 hv;
        hv.x = (f16)v.x; hv.y = (f16)v.y; hv.z = (f16)v.z; hv.w = (f16)v.w;
        *(f16x4*)(halo + xy * 16 + c4) = hv;
    }
    __syncthreads();

    // ================= conv 3x3x16 -> 128, bias, relu (two 8-row half-passes) =================
    for (int half = 0; half < 2; ++half) {
        f32x4 acc[2][8];
        #pragma unroll
        for (int ft = 0; ft < 2; ++ft) {
            f32x4 bias;
            bias.x = cb[fbase + ft * 16 + q * 4 + 0];
            bias.y = cb[fbase + ft * 16 + q * 4 + 1];
            bias.z = cb[fbase + ft * 16 + q * 4 + 2];
            bias.w = cb[fbase + ft * 16 + q * 4 + 3];
            #pragma unroll
            for (int p = 0; p < 8; ++p) acc[ft][p] = bias;
        }

        #pragma unroll
        for (int kc = 0; kc < 5; ++kc) {
            int tap = kc * 2 + (q >> 1);
            if (tap > 8) tap = 8;            // k>=144: weights are zero
            int dy = tap / 3, dx = tap - dy * 3;
            #pragma unroll
            for (int p = 0; p < 8; ++p) {
                int hy = half * 8 + p + dy;          // p-tile = pixel row
                int hx = l16 + dx;
                f16x8 bf = *(const f16x8*)(halo + (hy * 18 + hx) * 16 + (q & 1) * 8);
                #pragma unroll
                for (int ft = 0; ft < 2; ++ft)
                    acc[ft][p] = __builtin_amdgcn_mfma_f32_16x16x32_f16(cA[ft][kc], bf, acc[ft][p], 0, 0, 0);
            }
        }

        // relu in fp32, pack f16, write hs[px][f] (b64)
        #pragma unroll
        for (int ft = 0; ft < 2; ++ft)
            #pragma unroll
            for (int p = 0; p < 8; ++p) {
                f32x4 a = acc[ft][p];
                f16x4 pk;
                pk.x = (f16)fmaxf(a.x, 0.0f);
                pk.y = (f16)fmaxf(a.y, 0.0f);
                pk.z = (f16)fmaxf(a.z, 0.0f);
                pk.w = (f16)fmaxf(a.w, 0.0f);
                *(f16x4*)(hs + (half * 128 + p * 16 + l16) * HSS + fbase + ft * 16 + q * 4) = pk;
            }
    }
    __syncthreads();   // hs published; halo region dead -> aScr

    // ============ dense1 (128->256, relu) fused w/ dense2 (256->16) ============
    // All w1 fragments held in registers; p-outer reads each hB once.
    f16x8 dA[2][2][4];
    float b1v[2][2][4];
    #pragma unroll
    for (int jp = 0; jp < 2; ++jp)
        #pragma unroll
        for (int jt2 = 0; jt2 < 2; ++jt2) {
            #pragma unroll
            for (int kc = 0; kc < 4; ++kc)
                dA[jp][jt2][kc] = *(const f16x8*)(wb + OFF_W1 +
                    (size_t)(jbase + jp * 32 + jt2 * 16 + l16) * 128 + kc * 32 + q * 8);
            #pragma unroll
            for (int r = 0; r < 4; ++r)
                b1v[jp][jt2][r] = b1[jbase + jp * 32 + jt2 * 16 + q * 4 + r];
        }

    f32x4 dacc[16];   // PARTIAL over this wave's 64 j (AGPR-resident)
    #pragma unroll
    for (int p = 0; p < 16; ++p) { dacc[p].x = 0.f; dacc[p].y = 0.f; dacc[p].z = 0.f; dacc[p].w = 0.f; }

    f16* const myScr = aScr + (w * 16 + l16) * 40;

    for (int p = 0; p < 16; ++p) {
        f16x8 hB[4];
        #pragma unroll
        for (int kc = 0; kc < 4; ++kc)
            hB[kc] = *(const f16x8*)(hs + (p * 16 + l16) * HSS + kc * 32 + q * 8);

        #pragma unroll
        for (int jp = 0; jp < 2; ++jp) {
            #pragma unroll
            for (int jt2 = 0; jt2 < 2; ++jt2) {
                f32x4 a1;
                a1.x = b1v[jp][jt2][0]; a1.y = b1v[jp][jt2][1];
                a1.z = b1v[jp][jt2][2]; a1.w = b1v[jp][jt2][3];
                #pragma unroll
                for (int kc = 0; kc < 4; ++kc)
                    a1 = __builtin_amdgcn_mfma_f32_16x16x32_f16(dA[jp][jt2][kc], hB[kc], a1, 0, 0, 0);
                f16x4 pk;
                pk.x = (f16)fmaxf(a1.x, 0.0f);
                pk.y = (f16)fmaxf(a1.y, 0.0f);
                pk.z = (f16)fmaxf(a1.z, 0.0f);
                pk.w = (f16)fmaxf(a1.w, 0.0f);
                // D rows j32 = jt2*16+q*4+r, col px=l16 -> scratch[px][j32]
                *(f16x4*)(myScr + jt2 * 16 + q * 4) = pk;
            }
            // in-wave transpose readback: A-op [m=px=l16][k=q*8..]
            f16x8 af = *(const f16x8*)(myScr + q * 8);
            dacc[p] = __builtin_amdgcn_mfma_f32_16x16x32_f16(af, w2f[jp], dacc[p], 0, 0, 0);
        }
    }

    // ---- cross-wave reduction of dense2 partials ----
    __syncthreads();                         // all hs reads done -> redF may overwrite
    #pragma unroll
    for (int p = 0; p < 16; ++p)
        #pragma unroll
        for (int r = 0; r < 4; ++r) {
            int px = p * 16 + q * 4 + r;     // D row -> pixel, col l16 -> channel
            redF[(w * 256 + px) * RPS + l16] = dacc[p][r];
        }
    __syncthreads();

    // thread t = px, all 16 channels ; masked residual update (vectorized)
    {
        const int px = t;
        const int yy = px >> 4, xx = px & 15;
        const size_t pixb = ((size_t)(y0 + yy) * 64 + (x0 + xx)) * 16;
        const float a0 = gb[pixb];           // exact fp32 ch0
        const bool alive = (a0 > 0.1f);
        #pragma unroll
        for (int h = 0; h < 4; ++h) {
            const int ch = h * 4;
            f32x4 v0 = *(const f32x4*)(redF + (0 * 256 + px) * RPS + ch);
            f32x4 v1 = *(const f32x4*)(redF + (1 * 256 + px) * RPS + ch);
            f32x4 v2 = *(const f32x4*)(redF + (2 * 256 + px) * RPS + ch);
            f32x4 v3 = *(const f32x4*)(redF + (3 * 256 + px) * RPS + ch);
            f32x4 sv = v0 + v1 + v2 + v3;
            f32x4 gv = *(const f32x4*)(gb + pixb + ch);
            f32x4 ov;
            #pragma unroll
            for (int i = 0; i < 4; ++i) {
                int c = ch + i;
                float nv = gv[i];
                if (alive && c != 0) nv += sv[i] + b2[c];
                ov[i] = nv;
            }
            *(f32x4*)(gob + pixb + ch) = ov;
        }
    }
}

// ---------------- final softmax over channels 1..10 ----------------
__global__ void softmax_out(const float* __restrict__ g, float* __restrict__ out) {
    int pix = blockIdx.x * 256 + threadIdx.x;
    if (pix >= NPIX) return;
    const float* gp = g + (size_t)pix * 16;
    float v[10];
    float m = -1e30f;
    #pragma unroll
    for (int i = 0; i < 10; ++i) { v[i] = gp[1 + i]; m = fmaxf(m, v[i]); }
    float s = 0.f;
    #pragma unroll
    for (int i = 0; i < 10; ++i) { v[i] = __expf(v[i] - m); s += v[i]; }
    float inv = 1.0f / s;
    float* op = out + (size_t)pix * 10;
    #pragma unroll
    for (int i = 0; i < 10; ++i) op[i] = v[i] * inv;
}

extern "C" void kernel_launch(void* const* d_in, const int* in_sizes, int n_in,
                              void* d_out, int out_size, void* d_ws, size_t ws_size,
                              hipStream_t stream) {
    const float* inp = (const float*)d_in[0];
    const float* cw  = (const float*)d_in[1];
    const float* cb  = (const float*)d_in[2];
    const float* w1  = (const float*)d_in[3];
    const float* b1  = (const float*)d_in[4];
    const float* w2  = (const float*)d_in[5];
    const float* b2  = (const float*)d_in[6];
    float* out = (float*)d_out;

    // grid double-buffer in d_ws (32 MB, proven)
    float* g0 = (float*)d_ws;
    float* g1 = g0 + GRID_ELEMS;
    // f16 weights in d_out scratch (115 KB of 10.48 MB; softmax overwrites at end)
    f16* wb = (f16*)d_out;

    prep_weights<<<224, 256, 0, stream>>>(cw, w1, w2, wb);
    init_grid<<<(GRID_ELEMS + 255) / 256, 256, 0, stream>>>(inp, g0);

    float* bufs[2] = { g0, g1 };
    for (int s = 0; s < NSTEP; ++s) {
        nca_step<<<1024, 256, 0, stream>>>(bufs[s & 1], bufs[(s + 1) & 1],
                                           wb, cb, b1, b2);
    }
    // NSTEP=60 even -> final state in g0
    softmax_out<<<(NPIX + 255) / 256, 256, 0, stream>>>(g0, out);
}

// Round 14
// 2540.144 us; speedup vs baseline: 1.4549x; 1.0279x over previous
//
#include <hip/hip_runtime.h>
#include <math.h>

typedef _Float16 f16;
typedef f16  f16x8 __attribute__((ext_vector_type(8)));
typedef f16  f16x4 __attribute__((ext_vector_type(4)));
typedef float f32x4 __attribute__((ext_vector_type(4)));

#define NB 64
#define NC 16
#define NF 128
#define ND 256
#define NSTEP 60
#define GRID_ELEMS (NB*64*64*NC)   // 16 MB fp32
#define NPIX (NB*64*64)

#define KCONV 160                  // 9 taps * 16ch padded to 10 taps
#define HSS   136                  // hs row stride (f16) — balanced b128 pattern (at BW floor)
#define RPS   18                   // redF row stride (fp32): 2-way (free)
#define ASS   72                   // aScr row stride (f16): holds 2jp x 2jt2 dense1 outputs

// weight buffer layout (f16 elements) inside d_out scratch region
#define OFF_CW 0             // [128][160]
#define OFF_W1 20480         // [256][128]
#define OFF_W2 53248         // [16][256]

// ---------------- init: grid ch0 = input, others 0 ----------------
__global__ void init_grid(const float* __restrict__ inp, float* __restrict__ g) {
    int i = blockIdx.x * 256 + threadIdx.x;
    if (i >= GRID_ELEMS) return;
    int c = i & 15;
    g[i] = (c == 0) ? inp[i >> 4] : 0.0f;
}

// ---------------- prep: f16 transposed weights ----------------
__global__ void prep_weights(const float* __restrict__ cw, const float* __restrict__ w1,
                             const float* __restrict__ w2, f16* __restrict__ wb) {
    int i = blockIdx.x * 256 + threadIdx.x;   // 57344 threads exactly
    float v; int off, idx;
    if (i < 20480) {                          // cwT[f][k], k = tap*16+c (tap9 zero)
        int f = i / 160, k = i - f * 160;
        v = (k < 144) ? cw[k * 128 + f] : 0.0f;
        off = OFF_CW; idx = i;
    } else if (i < 20480 + 32768) {           // w1T[j][f]
        int r = i - 20480;
        int j = r >> 7, f = r & 127;
        v = w1[f * 256 + j];
        off = OFF_W1; idx = r;
    } else {                                  // w2T[c][j]
        int r = i - 20480 - 32768;
        int c = r >> 8, j = r & 255;
        v = w2[j * 16 + c];
        off = OFF_W2; idx = r;
    }
    wb[off + idx] = (f16)v;
}

// ---------------- fused NCA step (pure-f16 MFMA, fp32 accumulate/state) ----------------
// Block = 16x16 px tile (256 px), 256 threads = 4 waves, 1024 blocks/step.
// R13 structure + (a) batched dense2 transpose round trip (1 wait per p instead
// of 2), (b) XCD-swizzled block index (image's 16 tiles share one XCD's L2).
// Per-pixel arithmetic order identical to R13 -> bit-identical absmax.
__global__ __launch_bounds__(256, 2) void nca_step(
    const float* __restrict__ gin, float* __restrict__ gout,
    const f16* __restrict__ wb,
    const float* __restrict__ cb, const float* __restrict__ b1, const float* __restrict__ b2)
{
    // hs[256*136] (69632 B) + union{ halo [18*18][16] (10368 B) | aScr [64][72] (9216 B) }
    // redF (4*256*18 fp32 = 73728 B) overlays everything after dense phase.
    __shared__ f16 smem[40000];              // 80000 B
    f16* const hs   = smem;                  // 34816 elems
    f16* const un   = smem + 34816;          // 5184 elems
    f16* const halo = un;                    // [(hy*18+hx)]*16 + c
    f16* const aScr = un;                    // [4w*16px][ASS]
    float* const redF = (float*)smem;        // [4][256][RPS] fp32

    const int t    = threadIdx.x;
    const int w    = t >> 6;
    const int lane = t & 63;
    const int q    = lane >> 4;
    const int l16  = lane & 15;

    // XCD swizzle: d = xcd + 8*(tl + 16*ip), image b = xcd*8 + ip
    const int d  = blockIdx.x;
    const int b  = ((d & 7) << 3) | (d >> 7);
    const int tl = (d >> 3) & 15;
    const int y0 = (tl >> 2) << 4;
    const int x0 = (tl & 3) << 4;

    const float* gb  = gin  + (size_t)b * 64 * 64 * 16;
    float*       gob = gout + (size_t)b * 64 * 64 * 16;

    // ---- conv A-fragments + w2 fragments: issue global loads first ----
    const int fbase = w << 5;                // wave owns 32 filters
    f16x8 cA[2][5];
    #pragma unroll
    for (int ft = 0; ft < 2; ++ft)
        #pragma unroll
        for (int kc = 0; kc < 5; ++kc)
            cA[ft][kc] = *(const f16x8*)(wb + OFF_CW +
                (size_t)(fbase + ft * 16 + l16) * KCONV + kc * 32 + q * 8);
    const int jbase = w << 6;                // wave owns 64 j-columns
    f16x8 w2f[2];
    #pragma unroll
    for (int jp = 0; jp < 2; ++jp)
        w2f[jp] = *(const f16x8*)(wb + OFF_W2 + (size_t)l16 * 256 + jbase + jp * 32 + q * 8);

    // ---- stage halo (f16), zero-pad SAME; f32x4 global reads ----
    for (int i = t; i < 1296; i += 256) {    // 324 cells x 4 c-quads
        int c4 = (i & 3) << 2;
        int xy = i >> 2;
        int xx = xy % 18;
        int yy = xy / 18;
        int gy = y0 + yy - 1, gx = x0 + xx - 1;
        f32x4 v = {0.f, 0.f, 0.f, 0.f};
        if ((unsigned)gy < 64u && (unsigned)gx < 64u)
            v = *(const f32x4*)(gb + (gy * 64 + gx) * 16 + c4);
        f16x4 hv;
        hv.x = (f16)v.x; hv.y = (f16)v.y; hv.z = (f16)v.z; hv.w = (f16)v.w;
        *(f16x4*)(halo + xy * 16 + c4) = hv;
    }
    __syncthreads();

    // ================= conv 3x3x16 -> 128, bias, relu (two 8-row half-passes) =================
    for (int half = 0; half < 2; ++half) {
        f32x4 acc[2][8];
        #pragma unroll
        for (int ft = 0; ft < 2; ++ft) {
            f32x4 bias;
            bias.x = cb[fbase + ft * 16 + q * 4 + 0];
            bias.y = cb[fbase + ft * 16 + q * 4 + 1];
            bias.z = cb[fbase + ft * 16 + q * 4 + 2];
            bias.w = cb[fbase + ft * 16 + q * 4 + 3];
            #pragma unroll
            for (int p = 0; p < 8; ++p) acc[ft][p] = bias;
        }

        #pragma unroll
        for (int kc = 0; kc < 5; ++kc) {
            int tap = kc * 2 + (q >> 1);
            if (tap > 8) tap = 8;            // k>=144: weights are zero
            int dy = tap / 3, dx = tap - dy * 3;
            #pragma unroll
            for (int p = 0; p < 8; ++p) {
                int hy = half * 8 + p + dy;          // p-tile = pixel row
                int hx = l16 + dx;
                f16x8 bf = *(const f16x8*)(halo + (hy * 18 + hx) * 16 + (q & 1) * 8);
                #pragma unroll
                for (int ft = 0; ft < 2; ++ft)
                    acc[ft][p] = __builtin_amdgcn_mfma_f32_16x16x32_f16(cA[ft][kc], bf, acc[ft][p], 0, 0, 0);
            }
        }

        // relu in fp32, pack f16, write hs[px][f] (b64)
        #pragma unroll
        for (int ft = 0; ft < 2; ++ft)
            #pragma unroll
            for (int p = 0; p < 8; ++p) {
                f32x4 a = acc[ft][p];
                f16x4 pk;
                pk.x = (f16)fmaxf(a.x, 0.0f);
                pk.y = (f16)fmaxf(a.y, 0.0f);
                pk.z = (f16)fmaxf(a.z, 0.0f);
                pk.w = (f16)fmaxf(a.w, 0.0f);
                *(f16x4*)(hs + (half * 128 + p * 16 + l16) * HSS + fbase + ft * 16 + q * 4) = pk;
            }
    }
    __syncthreads();   // hs published; halo region dead -> aScr

    // ============ dense1 (128->256, relu) fused w/ dense2 (256->16) ============
    // All w1 fragments held in registers; p-outer reads each hB once.
    // Batched transpose: all 4 dense1 results written, ONE wait, 2 readbacks.
    f16x8 dA[2][2][4];
    float b1v[2][2][4];
    #pragma unroll
    for (int jp = 0; jp < 2; ++jp)
        #pragma unroll
        for (int jt2 = 0; jt2 < 2; ++jt2) {
            #pragma unroll
            for (int kc = 0; kc < 4; ++kc)
                dA[jp][jt2][kc] = *(const f16x8*)(wb + OFF_W1 +
                    (size_t)(jbase + jp * 32 + jt2 * 16 + l16) * 128 + kc * 32 + q * 8);
            #pragma unroll
            for (int r = 0; r < 4; ++r)
                b1v[jp][jt2][r] = b1[jbase + jp * 32 + jt2 * 16 + q * 4 + r];
        }

    f32x4 dacc[16];   // PARTIAL over this wave's 64 j (AGPR-resident)
    #pragma unroll
    for (int p = 0; p < 16; ++p) { dacc[p].x = 0.f; dacc[p].y = 0.f; dacc[p].z = 0.f; dacc[p].w = 0.f; }

    f16* const myScr = aScr + (w * 16 + l16) * ASS;

    for (int p = 0; p < 16; ++p) {
        f16x8 hB[4];
        #pragma unroll
        for (int kc = 0; kc < 4; ++kc)
            hB[kc] = *(const f16x8*)(hs + (p * 16 + l16) * HSS + kc * 32 + q * 8);

        #pragma unroll
        for (int jp = 0; jp < 2; ++jp)
            #pragma unroll
            for (int jt2 = 0; jt2 < 2; ++jt2) {
                f32x4 a1;
                a1.x = b1v[jp][jt2][0]; a1.y = b1v[jp][jt2][1];
                a1.z = b1v[jp][jt2][2]; a1.w = b1v[jp][jt2][3];
                #pragma unroll
                for (int kc = 0; kc < 4; ++kc)
                    a1 = __builtin_amdgcn_mfma_f32_16x16x32_f16(dA[jp][jt2][kc], hB[kc], a1, 0, 0, 0);
                f16x4 pk;
                pk.x = (f16)fmaxf(a1.x, 0.0f);
                pk.y = (f16)fmaxf(a1.y, 0.0f);
                pk.z = (f16)fmaxf(a1.z, 0.0f);
                pk.w = (f16)fmaxf(a1.w, 0.0f);
                // D rows j = jp*32 + jt2*16 + q*4 + r, col px=l16 -> scratch[px][j64]
                *(f16x4*)(myScr + jp * 32 + jt2 * 16 + q * 4) = pk;
            }
        // single wait, two readbacks: A-op [m=px=l16][k=q*8..] per jp
        f16x8 af0 = *(const f16x8*)(myScr + q * 8);
        f16x8 af1 = *(const f16x8*)(myScr + 32 + q * 8);
        dacc[p] = __builtin_amdgcn_mfma_f32_16x16x32_f16(af0, w2f[0], dacc[p], 0, 0, 0);
        dacc[p] = __builtin_amdgcn_mfma_f32_16x16x32_f16(af1, w2f[1], dacc[p], 0, 0, 0);
    }

    // ---- cross-wave reduction of dense2 partials ----
    __syncthreads();                         // all hs reads done -> redF may overwrite
    #pragma unroll
    for (int p = 0; p < 16; ++p)
        #pragma unroll
        for (int r = 0; r < 4; ++r) {
            int px = p * 16 + q * 4 + r;     // D row -> pixel, col l16 -> channel
            redF[(w * 256 + px) * RPS + l16] = dacc[p][r];
        }
    __syncthreads();

    // thread t = px, all 16 channels ; masked residual update (vectorized)
    {
        const int px = t;
        const int yy = px >> 4, xx = px & 15;
        const size_t pixb = ((size_t)(y0 + yy) * 64 + (x0 + xx)) * 16;
        const float a0 = gb[pixb];           // exact fp32 ch0
        const bool alive = (a0 > 0.1f);
        #pragma unroll
        for (int h = 0; h < 4; ++h) {
            const int ch = h * 4;
            f32x4 v0 = *(const f32x4*)(redF + (0 * 256 + px) * RPS + ch);
            f32x4 v1 = *(const f32x4*)(redF + (1 * 256 + px) * RPS + ch);
            f32x4 v2 = *(const f32x4*)(redF + (2 * 256 + px) * RPS + ch);
            f32x4 v3 = *(const f32x4*)(redF + (3 * 256 + px) * RPS + ch);
            f32x4 sv = v0 + v1 + v2 + v3;
            f32x4 gv = *(const f32x4*)(gb + pixb + ch);
            f32x4 ov;
            #pragma unroll
            for (int i = 0; i < 4; ++i) {
                int c = ch + i;
                float nv = gv[i];
                if (alive && c != 0) nv += sv[i] + b2[c];
                ov[i] = nv;
            }
            *(f32x4*)(gob + pixb + ch) = ov;
        }
    }
}

// ---------------- final softmax over channels 1..10 ----------------
__global__ void softmax_out(const float* __restrict__ g, float* __restrict__ out) {
    int pix = blockIdx.x * 256 + threadIdx.x;
    if (pix >= NPIX) return;
    const float* gp = g + (size_t)pix * 16;
    float v[10];
    float m = -1e30f;
    #pragma unroll
    for (int i = 0; i < 10; ++i) { v[i] = gp[1 + i]; m = fmaxf(m, v[i]); }
    float s = 0.f;
    #pragma unroll
    for (int i = 0; i < 10; ++i) { v[i] = __expf(v[i] - m); s += v[i]; }
    float inv = 1.0f / s;
    float* op = out + (size_t)pix * 10;
    #pragma unroll
    for (int i = 0; i < 10; ++i) op[i] = v[i] * inv;
}

extern "C" void kernel_launch(void* const* d_in, const int* in_sizes, int n_in,
                              void* d_out, int out_size, void* d_ws, size_t ws_size,
                              hipStream_t stream) {
    const float* inp = (const float*)d_in[0];
    const float* cw  = (const float*)d_in[1];
    const float* cb  = (const float*)d_in[2];
    const float* w1  = (const float*)d_in[3];
    const float* b1  = (const float*)d_in[4];
    const float* w2  = (const float*)d_in[5];
    const float* b2  = (const float*)d_in[6];
    float* out = (float*)d_out;

    // grid double-buffer in d_ws (32 MB, proven)
    float* g0 = (float*)d_ws;
    float* g1 = g0 + GRID_ELEMS;
    // f16 weights in d_out scratch (115 KB of 10.48 MB; softmax overwrites at end)
    f16* wb = (f16*)d_out;

    prep_weights<<<224, 256, 0, stream>>>(cw, w1, w2, wb);
    init_grid<<<(GRID_ELEMS + 255) / 256, 256, 0, stream>>>(inp, g0);

    float* bufs[2] = { g0, g1 };
    for (int s = 0; s < NSTEP; ++s) {
        nca_step<<<1024, 256, 0, stream>>>(bufs[s & 1], bufs[(s + 1) & 1],
                                           wb, cb, b1, b2);
    }
    // NSTEP=60 even -> final state in g0
    softmax_out<<<(NPIX + 255) / 256, 256, 0, stream>>>(g0, out);
}